// Round 12
// baseline (269.594 us; speedup 1.0000x reference)
//
#include <hip/hip_runtime.h>

// CavityModel forward: gaussian blur -> 3x(conv3d+maxpool+BN(batch stats)+leaky)
// -> dense 64->128 (+BN+leaky) -> 128->100 (+leaky) -> 100->20.
// R12: fuse conv2+conv3+dense1+dense2 into one persistent kernel (grid 256,
// 1 block/CU co-resident) with 3 device-scope atomic-spin grid barriers.
// Activations a2/a3/h1 stay in LDS; only BN stats cross blocks. splat/conv1
// untouched (R9-proven; R8/R10 showed conv1 datapath edits spill to scratch).

#define G2 324
#define G3 5832
#define NT 6
#define BATCH 256
#define APE 100
#define EPS 1e-5f

typedef unsigned short u16;
typedef unsigned int u32;
typedef _Float16 h2 __attribute__((ext_vector_type(2)));

__device__ __forceinline__ float leaky(float x) { return x >= 0.0f ? x : 0.01f * x; }
__device__ __forceinline__ u32 pkh(float a, float b) {
    h2 v; v[0] = (_Float16)a; v[1] = (_Float16)b;
    return __builtin_bit_cast(u32, v);
}
__device__ __forceinline__ float fdot2u(u32 a, u32 b, float c) {
#if __has_builtin(__builtin_amdgcn_fdot2)
    return __builtin_amdgcn_fdot2(__builtin_bit_cast(h2, a),
                                  __builtin_bit_cast(h2, b), c, false);
#else
    h2 x = __builtin_bit_cast(h2, a), y = __builtin_bit_cast(h2, b);
    return c + (float)x[0] * (float)y[0] + (float)x[1] * (float)y[1];
#endif
}
__device__ __forceinline__ float ldst(const float* p) {
    return __hip_atomic_load(p, __ATOMIC_RELAXED, __HIP_MEMORY_SCOPE_AGENT);
}
__device__ __forceinline__ void gbar(int* c, int n) {
    __syncthreads();
    if (threadIdx.x == 0) {
        __threadfence();
        __hip_atomic_fetch_add(c, 1, __ATOMIC_ACQ_REL, __HIP_MEMORY_SCOPE_AGENT);
        while (__hip_atomic_load(c, __ATOMIC_ACQUIRE, __HIP_MEMORY_SCOPE_AGENT) < n)
            __builtin_amdgcn_s_sleep(8);
    }
    __syncthreads();
}

// ---------- K1a: gaussian splat, separable outer product, NO atomics.
// block 0 zeroes bn-stats + barrier counters (runs strictly before consumers).
__global__ __launch_bounds__(512) void k_splat(const float* __restrict__ pos,
        const int* __restrict__ types, u32* __restrict__ fields,
        float* __restrict__ stO, int* __restrict__ ctr) {
    __shared__ float ew[APE * 54];
    __shared__ float ssum[APE * 3];
    __shared__ int list[APE];
    __shared__ int base[NT + 1];
    __shared__ int cnt[NT], cur[NT];
    const int b = blockIdx.x, tid = threadIdx.x;

    if (b == 0 && tid < 480) stO[tid] = 0.0f;
    if (b == 0 && tid >= 480 && tid < 484) ctr[tid - 480] = 0;
    if (tid < NT) { cnt[tid] = 0; cur[tid] = 0; }
    __syncthreads();
    if (tid < APE) atomicAdd(&cnt[types[b * APE + tid]], 1);
    if (tid < 300) {
        const int la = tid / 3, ax = tid % 3;
        const float p = pos[(b * APE + la) * 3 + ax];
        float s = 0.0f;
        #pragma unroll
        for (int g = 0; g < 18; ++g) {
            const float d = (float)g - 8.5f - p;
            const float e = __expf(d * d * (-1.0f / 0.72f));
            ew[la * 54 + ax * 18 + g] = e;
            s += e;
        }
        ssum[tid] = s;
    }
    __syncthreads();
    if (tid == 0) {
        int s = 0;
        #pragma unroll
        for (int t = 0; t < NT; ++t) { base[t] = s; s += cnt[t]; }
        base[NT] = s;
    }
    if (tid < APE) {
        const float inv = 1.0f / (ssum[tid * 3] * ssum[tid * 3 + 1] * ssum[tid * 3 + 2]);
        #pragma unroll
        for (int g = 0; g < 18; ++g) ew[tid * 54 + g] *= inv;
    }
    __syncthreads();
    if (tid < APE) {
        const int t = types[b * APE + tid];
        const int j = atomicAdd(&cur[t], 1);
        list[base[t] + j] = tid;
    }
    __syncthreads();

    for (int it = tid; it < NT * 324; it += 512) {
        const int t = it / 324, r = it - t * 324;
        const int i = r / 18, j = r % 18;
        float acc[18];
        #pragma unroll
        for (int k = 0; k < 18; ++k) acc[k] = 0.0f;
        const int e1 = base[t + 1];
        for (int u = base[t]; u < e1; ++u) {
            const int a = list[u];
            const float exy = ew[a * 54 + i] * ew[a * 54 + 18 + j];
            const float* ez = &ew[a * 54 + 36];
            #pragma unroll
            for (int k = 0; k < 18; ++k) acc[k] += exy * ez[k];
        }
        u32* dst = &fields[((size_t)b * NT + t) * 2916 + (size_t)r * 9];
        #pragma unroll
        for (int q = 0; q < 9; ++q) dst[q] = pkh(acc[2 * q], acc[2 * q + 1]);
    }
}

// ---------- K1b: conv1 — R9-PROVEN BODY, DO NOT RESTRUCTURE (R8/R10 spills).
template <int ZG>
__device__ __forceinline__ void conv1_pass(int c2, int Xl, int Yv, int b, int Xg,
        const u32* fldH, const u32* wpk, float* s_sum, float* s_ssq,
        const float* __restrict__ bias, float* __restrict__ a1) {
    float acc[2][2][2][6];
    #pragma unroll
    for (int c = 0; c < 2; ++c)
        #pragma unroll
        for (int o = 0; o < 2; ++o)
            #pragma unroll
            for (int p = 0; p < 2; ++p)
                #pragma unroll
                for (int z = 0; z < 6; ++z) acc[c][o][p][z] = 0.0f;

    for (int ic = 0; ic < 6; ++ic) {
        u32 A0[9], A1[9];
        float Bf0[9], Bf1[9];
        #pragma unroll
        for (int d2 = 0; d2 < 9; ++d2) {
            const int wb = ((ic * 9 + d2) * 8 + c2) * 3;
            A0[d2] = wpk[wb]; A1[d2] = wpk[wb + 1];
            const h2 w2 = __builtin_bit_cast(h2, wpk[wb + 2]);
            Bf0[d2] = (float)w2[0]; Bf1[d2] = (float)w2[1];
        }
        #pragma unroll
        for (int lj = 0; lj < 4; ++lj) {
            const int iy = 2 * Yv + lj - 1;
            const bool yok = (iy >= 0 && iy < 18);
            #pragma unroll
            for (int li = 0; li < 4; ++li) {
                const int ixl = 2 * Xl + li;
                u32 V[5], Sh[4];
                if (yok) {
                    const u32* rp = &fldH[((ic * 8 + ixl) * 18 + iy) * 10];
                    if (ZG == 0) {
                        V[0] = 0u;
                        #pragma unroll
                        for (int q = 0; q < 4; ++q) V[q + 1] = rp[q];
                    } else {
                        #pragma unroll
                        for (int q = 0; q < 5; ++q) V[q] = rp[3 * ZG - 1 + q];
                    }
                } else {
                    #pragma unroll
                    for (int q = 0; q < 5; ++q) V[q] = 0u;
                }
                #pragma unroll
                for (int q = 0; q < 4; ++q)
                    Sh[q] = __builtin_amdgcn_alignbit(V[q + 1], V[q], 16);
                float vlo[3], vhi[3];
                #pragma unroll
                for (int q = 0; q < 3; ++q) {
                    const h2 hv = __builtin_bit_cast(h2, V[q + 2]);
                    vlo[q] = (float)hv[0];
                    const h2 hw = __builtin_bit_cast(h2, V[q + 1]);
                    vhi[q] = (float)hw[1];
                }
                #pragma unroll
                for (int o = 0; o < 2; ++o) {
                    const int dx = li - o;
                    if (dx < 0 || dx > 2) continue;
                    #pragma unroll
                    for (int p = 0; p < 2; ++p) {
                        const int dy = lj - p;
                        if (dy < 0 || dy > 2) continue;
                        const int d2 = dx * 3 + dy;
                        #pragma unroll
                        for (int ozl = 0; ozl < 6; ++ozl) {
                            if (ozl & 1) {
                                const int vi = (ozl + 1) >> 1;
                                acc[0][o][p][ozl] = fdot2u(A0[d2], V[vi],
                                    fmaf(Bf0[d2], vlo[vi - 1], acc[0][o][p][ozl]));
                                acc[1][o][p][ozl] = fdot2u(A1[d2], V[vi],
                                    fmaf(Bf1[d2], vlo[vi - 1], acc[1][o][p][ozl]));
                            } else {
                                const int si = ozl >> 1;
                                acc[0][o][p][ozl] = fdot2u(A0[d2], Sh[si],
                                    fmaf(Bf0[d2], vhi[si], acc[0][o][p][ozl]));
                                acc[1][o][p][ozl] = fdot2u(A1[d2], Sh[si],
                                    fmaf(Bf1[d2], vhi[si], acc[1][o][p][ozl]));
                            }
                        }
                    }
                }
            }
        }
    }
    const float bb0 = bias[2 * c2], bb1 = bias[2 * c2 + 1];
    float s0 = 0.0f, q0 = 0.0f, s1 = 0.0f, q1 = 0.0f;
    #pragma unroll
    for (int Zp = 0; Zp < 3; ++Zp) {
        float m0 = acc[0][0][0][2 * Zp], m1 = acc[1][0][0][2 * Zp];
        #pragma unroll
        for (int o = 0; o < 2; ++o)
            #pragma unroll
            for (int p = 0; p < 2; ++p) {
                m0 = fmaxf(m0, fmaxf(acc[0][o][p][2 * Zp], acc[0][o][p][2 * Zp + 1]));
                m1 = fmaxf(m1, fmaxf(acc[1][o][p][2 * Zp], acc[1][o][p][2 * Zp + 1]));
            }
        float2 vv; vv.x = m0 + bb0; vv.y = m1 + bb1;
        s0 += vv.x; q0 += vv.x * vv.x; s1 += vv.y; q1 += vv.y * vv.y;
        const int spg = (3 * Xg + Xl) * 81 + Yv * 9 + 3 * ZG + Zp;
        *(float2*)&a1[((size_t)b * 729 + spg) * 16 + 2 * c2] = vv;
    }
    atomicAdd(&s_sum[2 * c2], s0);     atomicAdd(&s_ssq[2 * c2], q0);
    atomicAdd(&s_sum[2 * c2 + 1], s1); atomicAdd(&s_ssq[2 * c2 + 1], q1);
}

__global__ __launch_bounds__(256, 3) void k_conv1(const u32* __restrict__ fields,
        const float* __restrict__ w, const float* __restrict__ bias,
        float* __restrict__ a1, float* __restrict__ stO) {
    __shared__ u32 fldH[48 * 18 * 10];
    __shared__ u32 wpk[432 * 3];
    __shared__ float s_sum[16], s_ssq[16];
    const int bx = blockIdx.x, b = bx / 3, Xg = bx % 3, tid = threadIdx.x;

    for (int i = tid; i < 432; i += 256) {
        const int c2 = i & 7, t = i >> 3, d2 = t % 9, ic = t / 9;
        const int w0 = (2 * c2) * 162 + ic * 27 + d2 * 3;
        const int w1 = w0 + 162;
        wpk[i * 3]     = pkh(w[w0], w[w0 + 1]);
        wpk[i * 3 + 1] = pkh(w[w1], w[w1 + 1]);
        wpk[i * 3 + 2] = pkh(w[w0 + 2], w[w1 + 2]);
    }
    if (tid < 16) { s_sum[tid] = 0.0f; s_ssq[tid] = 0.0f; }
    for (int i = tid; i < 8640; i += 256) {
        const int p = i % 10, t = i / 10;
        const int iy = t % 18, a = t / 18;
        const int ix = 6 * Xg - 1 + (a & 7);
        u32 v = 0;
        if (p < 9 && ix >= 0 && ix < 18)
            v = fields[((size_t)(b * 6 + (a >> 3)) * 324 + ix * 18 + iy) * 9 + p];
        fldH[t * 10 + p] = v;
    }
    __syncthreads();

    const int c2 = tid & 7, sp = tid >> 3;
    if (tid < 216) {
        const int Xl = sp / 9, Yv = sp % 9;
        conv1_pass<0>(c2, Xl, Yv, b, Xg, fldH, wpk, s_sum, s_ssq, bias, a1);
        conv1_pass<1>(c2, Xl, Yv, b, Xg, fldH, wpk, s_sum, s_ssq, bias, a1);
        conv1_pass<2>(c2, Xl, Yv, b, Xg, fldH, wpk, s_sum, s_ssq, bias, a1);
    }
    __syncthreads();
    if (tid < 16) { atomicAdd(&stO[tid], s_sum[tid]); atomicAdd(&stO[16 + tid], s_ssq[tid]); }
}

// ---------- K2: persistent tail — conv2 -> [gbar] -> conv3 -> [gbar] ->
// dense1 -> [gbar] -> dense2. grid 256 (1 block/CU, co-resident by LDS size).
// a2/a3/h1 live in LDS; only stats cross blocks (device-scope atomics).
__global__ __launch_bounds__(512) void k_tail(const float* __restrict__ a1,
        const float* __restrict__ w2c, const float* __restrict__ b2c,
        const float* __restrict__ bn1g, const float* __restrict__ bn1b,
        const float* __restrict__ w3c, const float* __restrict__ b3c,
        const float* __restrict__ bn2g, const float* __restrict__ bn2b,
        const float* __restrict__ d1w, const float* __restrict__ d1b,
        const float* __restrict__ bn3g, const float* __restrict__ bn3b,
        const float* __restrict__ d2w, const float* __restrict__ d2b,
        const float* __restrict__ bn4g, const float* __restrict__ bn4b,
        const float* __restrict__ d3w, const float* __restrict__ d3b,
        float* __restrict__ st, int* __restrict__ ctr,
        float* __restrict__ out) {
    __shared__ float xin[16 * 729];     // 46656 B
    __shared__ float ws2[13824];        // 55296 B
    __shared__ float a2l[864];
    __shared__ float x3[864];
    __shared__ float pacc[512 * 8];     // 16384 B
    __shared__ float a3l[64], h1l[128], xc[128], yv[100];
    __shared__ float sc[32], sh[32], s_sum[32], s_ssq[32];
    const int b = blockIdx.x, tid = threadIdx.x;

    // ---- phase A: bn1+leaky -> conv2 (16->32, pad0) + pool -> a2l + bn2 stats
    if (tid < 16) {
        const float cntc = 256.0f * 729.0f;
        float m = st[tid] / cntc;                       // bn1 stats: prev kernel
        float v = st[16 + tid] / cntc - m * m;
        float s = bn1g[tid] * rsqrtf(fmaxf(v, 0.0f) + EPS);
        sc[tid] = s; sh[tid] = bn1b[tid] - m * s;
    }
    if (tid < 32) { s_sum[tid] = 0.0f; s_ssq[tid] = 0.0f; }
    __syncthreads();
    const float* src = a1 + (size_t)b * 729 * 16;
    for (int i = tid; i < 16 * 729; i += 512) {
        const int spb = i >> 4, c = i & 15;
        xin[c * 729 + spb] = leaky(src[i] * sc[c] + sh[c]);
    }
    for (int i = tid; i < 13824; i += 512) ws2[i] = w2c[i];
    __syncthreads();
    for (int idx = tid; idx < 576; idx += 512) {
        const int oyi = idx & 1, oxi = (idx >> 1) & 1, rest = idx >> 2;
        const int Y = rest % 3, X = (rest / 3) % 3, c2 = rest / 9;   // 0..15
        const int ox = 2 * X + oxi, oy = 2 * Y + oyi;
        const int c0 = 2 * c2, c1 = c0 + 1;
        float acc0[6], acc1[6];
        #pragma unroll
        for (int z = 0; z < 6; ++z) { acc0[z] = 0.0f; acc1[z] = 0.0f; }
        for (int ic = 0; ic < 16; ++ic) {
            #pragma unroll
            for (int dx = 0; dx < 3; ++dx) {
                const int ix = ox + dx;
                #pragma unroll
                for (int dy = 0; dy < 3; ++dy) {
                    const int iy = oy + dy;
                    const float* rp = &xin[ic * 729 + ix * 81 + iy * 9];
                    float row[9];
                    #pragma unroll
                    for (int z = 0; z < 9; ++z) row[z] = rp[z];
                    const int wb0 = (c0 * 16 + ic) * 27 + dx * 9 + dy * 3;
                    const int wb1 = (c1 * 16 + ic) * 27 + dx * 9 + dy * 3;
                    #pragma unroll
                    for (int dz = 0; dz < 3; ++dz) {
                        const float w0 = ws2[wb0 + dz];
                        const float w1v = ws2[wb1 + dz];
                        #pragma unroll
                        for (int z = 0; z < 6; ++z) {
                            acc0[z] += w0 * row[z + dz];
                            acc1[z] += w1v * row[z + dz];
                        }
                    }
                }
            }
        }
        float pl[2][3];
        #pragma unroll
        for (int Z = 0; Z < 3; ++Z) {
            float v0 = fmaxf(acc0[2 * Z], acc0[2 * Z + 1]);
            float v1 = fmaxf(acc1[2 * Z], acc1[2 * Z + 1]);
            v0 = fmaxf(v0, __shfl_xor(v0, 1)); v0 = fmaxf(v0, __shfl_xor(v0, 2));
            v1 = fmaxf(v1, __shfl_xor(v1, 1)); v1 = fmaxf(v1, __shfl_xor(v1, 2));
            pl[0][Z] = v0; pl[1][Z] = v1;
        }
        if ((idx & 3) == 0) {
            #pragma unroll
            for (int hh = 0; hh < 2; ++hh) {
                const int c = c0 + hh;
                const float bb = b2c[c];
                float s0 = 0.0f, q0 = 0.0f;
                #pragma unroll
                for (int Z = 0; Z < 3; ++Z) {
                    const float v = pl[hh][Z] + bb;
                    a2l[c * 27 + X * 9 + Y * 3 + Z] = v;
                    s0 += v; q0 += v * v;
                }
                atomicAdd(&s_sum[c], s0); atomicAdd(&s_ssq[c], q0);
            }
        }
    }
    __syncthreads();
    if (tid < 32) { atomicAdd(&st[32 + tid], s_sum[tid]); atomicAdd(&st[64 + tid], s_ssq[tid]); }
    gbar(&ctr[0], BATCH);

    // ---- phase B: bn2+leaky -> conv3 (32->64, pad1) + pool -> a3l + bn3 stats
    if (tid < 32) {
        const float cntc = 256.0f * 27.0f;
        float m = ldst(&st[32 + tid]) / cntc;
        float v = ldst(&st[64 + tid]) / cntc - m * m;
        float s = bn2g[tid] * rsqrtf(fmaxf(v, 0.0f) + EPS);
        sc[tid] = s; sh[tid] = bn2b[tid] - m * s;
    }
    __syncthreads();
    for (int i = tid; i < 864; i += 512) {
        const int c = i / 27;
        x3[i] = leaky(a2l[i] * sc[c] + sh[c]);
    }
    __syncthreads();
    {
        const int c = tid & 63, q = tid >> 6;   // q 0..7, 4 ic each
        float acc[8];
        #pragma unroll
        for (int p = 0; p < 8; ++p) acc[p] = 0.0f;
        for (int ic = q * 4; ic < q * 4 + 4; ++ic) {
            const float* wr = w3c + ((size_t)c * 32 + ic) * 27;
            #pragma unroll
            for (int d = 0; d < 27; ++d) {
                const int dx = d / 9, dy = (d / 3) % 3, dz = d % 3;
                const float wv = wr[d];
                #pragma unroll
                for (int p = 0; p < 8; ++p) {
                    const int px = p >> 2, py = (p >> 1) & 1, pz = p & 1;
                    const int ix = px + dx - 1, iy = py + dy - 1, iz = pz + dz - 1;
                    if (ix >= 0 && iy >= 0 && iz >= 0)
                        acc[p] += wv * x3[ic * 27 + ix * 9 + iy * 3 + iz];
                }
            }
        }
        #pragma unroll
        for (int p = 0; p < 8; ++p) pacc[tid * 8 + p] = acc[p];
    }
    __syncthreads();
    if (tid < 64) {
        const int c = tid;
        float m = -1e30f;
        #pragma unroll
        for (int p = 0; p < 8; ++p) {
            float v = 0.0f;
            #pragma unroll
            for (int qq = 0; qq < 8; ++qq) v += pacc[(qq * 64 + c) * 8 + p];
            m = fmaxf(m, v);
        }
        const float v = m + b3c[c];
        a3l[c] = v;
        atomicAdd(&st[96 + c], v); atomicAdd(&st[160 + c], v * v);
    }
    gbar(&ctr[1], BATCH);

    // ---- phase C: bn3+leaky -> dense 64->128 -> h1l + bn4 stats
    if (tid < 64) {
        float m = ldst(&st[96 + tid]) / 256.0f;
        float v = ldst(&st[160 + tid]) / 256.0f - m * m;
        float s = bn3g[tid] * rsqrtf(fmaxf(v, 0.0f) + EPS);
        xc[tid] = leaky(a3l[tid] * s + (bn3b[tid] - m * s));
    }
    __syncthreads();
    if (tid < 128) {
        const float* wr = d1w + tid * 64;
        float acc = d1b[tid];
        #pragma unroll
        for (int i = 0; i < 64; ++i) acc += xc[i] * wr[i];
        h1l[tid] = acc;
        atomicAdd(&st[224 + tid], acc); atomicAdd(&st[352 + tid], acc * acc);
    }
    gbar(&ctr[2], BATCH);

    // ---- phase D: bn4+leaky -> 128->100 (+leaky) -> 100->20 -> out
    if (tid < 128) {
        float m = ldst(&st[224 + tid]) / 256.0f;
        float v = ldst(&st[352 + tid]) / 256.0f - m * m;
        float s = bn4g[tid] * rsqrtf(fmaxf(v, 0.0f) + EPS);
        xc[tid] = leaky(h1l[tid] * s + (bn4b[tid] - m * s));
    }
    __syncthreads();
    if (tid < 100) {
        const float* wr = d2w + tid * 128;
        float acc = d2b[tid];
        #pragma unroll
        for (int i = 0; i < 128; ++i) acc += xc[i] * wr[i];
        yv[tid] = leaky(acc);
    }
    __syncthreads();
    if (tid < 20) {
        const float* wr = d3w + tid * 100;
        float acc = d3b[tid];
        #pragma unroll
        for (int i = 0; i < 100; ++i) acc += yv[i] * wr[i];
        out[(size_t)b * 20 + tid] = acc;
    }
}

extern "C" void kernel_launch(void* const* d_in, const int* in_sizes, int n_in,
                              void* d_out, int out_size, void* d_ws, size_t ws_size,
                              hipStream_t stream) {
    (void)in_sizes; (void)n_in; (void)out_size; (void)ws_size;
    const float* pos  = (const float*)d_in[0];
    const float* c1w  = (const float*)d_in[1];
    const float* c1b  = (const float*)d_in[2];
    const float* bn1g = (const float*)d_in[3];
    const float* bn1b = (const float*)d_in[4];
    const float* c2w  = (const float*)d_in[5];
    const float* c2b  = (const float*)d_in[6];
    const float* bn2g = (const float*)d_in[7];
    const float* bn2b = (const float*)d_in[8];
    const float* c3w  = (const float*)d_in[9];
    const float* c3b  = (const float*)d_in[10];
    const float* bn3g = (const float*)d_in[11];
    const float* bn3b = (const float*)d_in[12];
    const float* d1w  = (const float*)d_in[13];
    const float* d1b  = (const float*)d_in[14];
    const float* bn4g = (const float*)d_in[15];
    const float* bn4b = (const float*)d_in[16];
    const float* d2w  = (const float*)d_in[17];
    const float* d2b  = (const float*)d_in[18];
    const float* d3w  = (const float*)d_in[19];
    const float* d3b  = (const float*)d_in[20];
    const int* types  = (const int*)d_in[22];   // d_in[21]=batch_ids implied by layout

    float* ws = (float*)d_ws;
    float* st = ws;                         // 480 f bn stats; ints 480..483 = ctr
    int* ctr = (int*)(ws + 480);
    float* a1 = ws + 512;                   // 2,985,984 f  [b][729][16]
    u32* fields = (u32*)(a1 + 2985984);     // f16 pairs: 4,478,976 u32 (~30 MB)

    k_splat <<<BATCH, 512, 0, stream>>>(pos, types, fields, st, ctr);
    k_conv1 <<<3 * BATCH, 256, 0, stream>>>(fields, c1w, c1b, a1, st);
    k_tail  <<<BATCH, 512, 0, stream>>>(a1, c2w, c2b, bn1g, bn1b, c3w, c3b,
                                        bn2g, bn2b, d1w, d1b, bn3g, bn3b,
                                        d2w, d2b, bn4g, bn4b, d3w, d3b,
                                        st, ctr, (float*)d_out);
}

// Round 14
// 214.507 us; speedup vs baseline: 1.2568x; 1.2568x over previous
//
#include <hip/hip_runtime.h>

// CavityModel forward: gaussian blur -> 3x(conv3d+maxpool+BN(batch stats)+leaky)
// -> dense 64->128 (+BN+leaky) -> 128->100 (+leaky) -> 100->20.
// R14: R13's MFMA conv1 with the column-base off-by-one fixed:
// cb = oxl*400 + oy*20 + oz (stage writes input iy,iz at padded index iy+1,iz+1;
// tap needs array index oy+dy, and koff already contributes dy*20+dz).

#define G2 324
#define G3 5832
#define NT 6
#define BATCH 256
#define APE 100
#define EPS 1e-5f

typedef unsigned short u16;
typedef unsigned int u32;
typedef _Float16 f16;
typedef _Float16 h2 __attribute__((ext_vector_type(2)));
typedef _Float16 f16x8 __attribute__((ext_vector_type(8)));
typedef float f32x4 __attribute__((ext_vector_type(4)));

__device__ __forceinline__ float leaky(float x) { return x >= 0.0f ? x : 0.01f * x; }
__device__ __forceinline__ u32 pkh(float a, float b) {
    h2 v; v[0] = (f16)a; v[1] = (f16)b;
    return __builtin_bit_cast(u32, v);
}

// ---------- K1a: gaussian splat, separable outer product, NO atomics.
// block 0 zeroes the bn-stats buffer (runs strictly before all consumers).
__global__ __launch_bounds__(512) void k_splat(const float* __restrict__ pos,
        const int* __restrict__ types, u32* __restrict__ fields,
        float* __restrict__ stO) {
    __shared__ float ew[APE * 54];
    __shared__ float ssum[APE * 3];
    __shared__ int list[APE];
    __shared__ int base[NT + 1];
    __shared__ int cnt[NT], cur[NT];
    const int b = blockIdx.x, tid = threadIdx.x;

    if (b == 0 && tid < 480) stO[tid] = 0.0f;
    if (tid < NT) { cnt[tid] = 0; cur[tid] = 0; }
    __syncthreads();
    if (tid < APE) atomicAdd(&cnt[types[b * APE + tid]], 1);
    if (tid < 300) {
        const int la = tid / 3, ax = tid % 3;
        const float p = pos[(b * APE + la) * 3 + ax];
        float s = 0.0f;
        #pragma unroll
        for (int g = 0; g < 18; ++g) {
            const float d = (float)g - 8.5f - p;
            const float e = __expf(d * d * (-1.0f / 0.72f));
            ew[la * 54 + ax * 18 + g] = e;
            s += e;
        }
        ssum[tid] = s;
    }
    __syncthreads();
    if (tid == 0) {
        int s = 0;
        #pragma unroll
        for (int t = 0; t < NT; ++t) { base[t] = s; s += cnt[t]; }
        base[NT] = s;
    }
    if (tid < APE) {
        const float inv = 1.0f / (ssum[tid * 3] * ssum[tid * 3 + 1] * ssum[tid * 3 + 2]);
        #pragma unroll
        for (int g = 0; g < 18; ++g) ew[tid * 54 + g] *= inv;
    }
    __syncthreads();
    if (tid < APE) {
        const int t = types[b * APE + tid];
        const int j = atomicAdd(&cur[t], 1);
        list[base[t] + j] = tid;
    }
    __syncthreads();

    for (int it = tid; it < NT * 324; it += 512) {
        const int t = it / 324, r = it - t * 324;
        const int i = r / 18, j = r % 18;
        float acc[18];
        #pragma unroll
        for (int k = 0; k < 18; ++k) acc[k] = 0.0f;
        const int e1 = base[t + 1];
        for (int u = base[t]; u < e1; ++u) {
            const int a = list[u];
            const float exy = ew[a * 54 + i] * ew[a * 54 + 18 + j];
            const float* ez = &ew[a * 54 + 36];
            #pragma unroll
            for (int k = 0; k < 18; ++k) acc[k] += exy * ez[k];
        }
        u32* dst = &fields[((size_t)b * NT + t) * 2916 + (size_t)r * 9];
        #pragma unroll
        for (int q = 0; q < 9; ++q) dst[q] = pkh(acc[2 * q], acc[2 * q + 1]);
    }
}

// ---------- K1b: conv1 via MFMA implicit GEMM + 2x2x2 pool + bias + bn1 stats
// block = (env b, x-pair Xg 0..8); grid bx = b*9 + Xg (same-env adjacent).
// input tile fldP[ic 6][plane 4][y 20][z 20] f16, zero-padded halo.
// A = W[16 oc][192 k] (k = ic*27 + dx*9 + dy*3 + dz; k>=162 zero) in regs.
// B[k][16 spatial] built per tile: addr = colbase(spatial) + koffT[k].
// k-mapping within lane is permutation-invariant (same map for A and B).
__global__ __launch_bounds__(256, 3) void k_conv1(const u32* __restrict__ fields,
        const float* __restrict__ w, const float* __restrict__ bias,
        float* __restrict__ a1, float* __restrict__ stO) {
    __shared__ f16 fldP[9600];     // 19200 B: [ic][pl][y][z] strides 1600/400/20/1
    __shared__ f16 outB[16 * 648]; // 20736 B: conv out [oc][s], s = oxl*324+oy*18+oz
    __shared__ u16 koffT[192];     // element offsets per k
    __shared__ float bs[16], s_sum[16], s_ssq[16];
    const int bx = blockIdx.x, b = bx / 9, Xg = bx % 9, tid = threadIdx.x;

    for (int i = tid; i < 4800; i += 256) ((u32*)fldP)[i] = 0u;
    if (tid < 192) {
        u16 off = 0;
        if (tid < 162) {
            const int ic = tid / 27, d = tid % 27;
            off = (u16)(ic * 1600 + (d / 9) * 400 + ((d / 3) % 3) * 20 + (d % 3));
        }
        koffT[tid] = off;
    }
    if (tid < 16) { bs[tid] = bias[tid]; s_sum[tid] = 0.0f; s_ssq[tid] = 0.0f; }

    // A fragments: lane m = lane&15 (oc), k = 32c + 8g + j (g = lane>>4)
    const int lane = tid & 63, g = lane >> 4, m = lane & 15, wv = tid >> 6;
    f16x8 af[6];
    #pragma unroll
    for (int c = 0; c < 6; ++c)
        #pragma unroll
        for (int j = 0; j < 8; ++j) {
            const int k = 32 * c + 8 * g + j;
            af[c][j] = (k < 162) ? (f16)w[m * 162 + k] : (f16)0.0f;
        }
    __syncthreads();

    // stage interior: planes ix = 2Xg-1 .. 2Xg+2 (pads stay zero)
    for (int i = tid; i < 3888; i += 256) {
        const int p = i % 9, r2 = i / 9, iy = r2 % 18, r3 = r2 / 18;
        const int pl = r3 & 3, ic = r3 >> 2;
        const int ix = 2 * Xg - 1 + pl;
        if (ix >= 0 && ix < 18) {
            const u32 v = fields[((size_t)(b * 6 + ic) * 324 + ix * 18 + iy) * 9 + p];
            const h2 hv = __builtin_bit_cast(h2, v);
            const int e = ic * 1600 + pl * 400 + (iy + 1) * 20 + (2 * p + 1);
            fldP[e] = hv[0];
            fldP[e + 1] = hv[1];
        }
    }
    __syncthreads();

    // MFMA over 41 spatial tiles of 16 (648 positions, last tile ragged)
    for (int t = wv; t < 41; t += 4) {
        const int s = 16 * t + m;
        const int sv = (s < 648) ? s : 647;
        const int oxl = sv / 324, rem = sv % 324, oy = rem / 18, oz = rem % 18;
        // stage writes input (iy,iz) at padded index (iy+1,iz+1); tap needs
        // array index oy+dy (iy=oy+dy-1), koff contributes dy*20+dz -> base oy,oz.
        const int cb = oxl * 400 + oy * 20 + oz;
        f32x4 acc = {0.0f, 0.0f, 0.0f, 0.0f};
        #pragma unroll
        for (int c = 0; c < 6; ++c) {
            const int kb = 32 * c + 8 * g;
            f16x8 bf;
            #pragma unroll
            for (int j = 0; j < 8; ++j)
                bf[j] = fldP[cb + (int)koffT[kb + j]];
            acc = __builtin_amdgcn_mfma_f32_16x16x32_f16(af[c], bf, acc, 0, 0, 0);
        }
        if (s < 648) {
            #pragma unroll
            for (int r = 0; r < 4; ++r)
                outB[(4 * g + r) * 648 + s] = (f16)acc[r];
        }
    }
    __syncthreads();

    // 2x2x2 pool + bias -> a1 [b][spatial 729][ch 16] + bn1 stats
    for (int i = tid; i < 1296; i += 256) {
        const int oc = i & 15, sp = i >> 4, Y = sp / 9, Z = sp % 9;
        float mx = -1e30f;
        #pragma unroll
        for (int u = 0; u < 8; ++u) {
            const int ox = u >> 2, dy = (u >> 1) & 1, dz = u & 1;
            mx = fmaxf(mx, (float)outB[oc * 648 + ox * 324
                                       + (2 * Y + dy) * 18 + (2 * Z + dz)]);
        }
        const float v = mx + bs[oc];
        a1[((size_t)b * 729 + Xg * 81 + Y * 9 + Z) * 16 + oc] = v;
        atomicAdd(&s_sum[oc], v);
        atomicAdd(&s_ssq[oc], v * v);
    }
    __syncthreads();
    if (tid < 16) { atomicAdd(&stO[tid], s_sum[tid]); atomicAdd(&stO[16 + tid], s_ssq[tid]); }
}

// ---------- K2: bn1+leaky -> conv2 (16->32, pad0) + pool -> [32,3^3] + bn2 stats
// oc-split: block = (env, half); grid 2*BATCH (same-env adjacent); 320 threads.
__global__ __launch_bounds__(320) void k_conv2(const float* __restrict__ a1,
        const float* __restrict__ w, const float* __restrict__ bias,
        const float* __restrict__ bng, const float* __restrict__ bnb,
        const float* __restrict__ stI, float* __restrict__ a2,
        float* __restrict__ stO) {
    __shared__ float xin[16 * 729];     // 46656 B
    __shared__ float ws2[6912];         // half of weights: 27648 B
    __shared__ float sc[16], sh[16];
    __shared__ float s_sum[16], s_ssq[16];
    const int bx = blockIdx.x, b = bx >> 1, half = bx & 1, tid = threadIdx.x;
    if (tid < 16) {
        const float cnt = 256.0f * 729.0f;
        float m = stI[tid] / cnt;
        float v = stI[16 + tid] / cnt - m * m;
        float s = bng[tid] * rsqrtf(fmaxf(v, 0.0f) + EPS);
        sc[tid] = s; sh[tid] = bnb[tid] - m * s;
        s_sum[tid] = 0.0f; s_ssq[tid] = 0.0f;
    }
    __syncthreads();
    const float* src = a1 + (size_t)b * 729 * 16;
    for (int i = tid; i < 16 * 729; i += 320) {
        const int spb = i >> 4, c = i & 15;
        xin[c * 729 + spb] = leaky(src[i] * sc[c] + sh[c]);
    }
    for (int i = tid; i < 6912; i += 320) ws2[i] = w[half * 6912 + i];
    __syncthreads();
    if (tid < 288) {
        const int oyi = tid & 1, oxi = (tid >> 1) & 1, rest = tid >> 2;
        const int Y = rest % 3, X = (rest / 3) % 3, c2 = rest / 9;   // c2 0..7
        const int ox = 2 * X + oxi, oy = 2 * Y + oyi;   // 0..5
        const int cl0 = 2 * c2, cl1 = cl0 + 1;
        float acc0[6], acc1[6];
        #pragma unroll
        for (int z = 0; z < 6; ++z) { acc0[z] = 0.0f; acc1[z] = 0.0f; }
        for (int ic = 0; ic < 16; ++ic) {
            #pragma unroll
            for (int dx = 0; dx < 3; ++dx) {
                const int ix = ox + dx;
                #pragma unroll
                for (int dy = 0; dy < 3; ++dy) {
                    const int iy = oy + dy;
                    const float* rp = &xin[ic * 729 + ix * 81 + iy * 9];
                    float row[9];
                    #pragma unroll
                    for (int z = 0; z < 9; ++z) row[z] = rp[z];
                    const int wb0 = (cl0 * 16 + ic) * 27 + dx * 9 + dy * 3;
                    const int wb1 = (cl1 * 16 + ic) * 27 + dx * 9 + dy * 3;
                    #pragma unroll
                    for (int dz = 0; dz < 3; ++dz) {
                        const float w0 = ws2[wb0 + dz];
                        const float w1v = ws2[wb1 + dz];
                        #pragma unroll
                        for (int z = 0; z < 6; ++z) {
                            acc0[z] += w0 * row[z + dz];
                            acc1[z] += w1v * row[z + dz];
                        }
                    }
                }
            }
        }
        float pl[2][3];
        #pragma unroll
        for (int Z = 0; Z < 3; ++Z) {
            float v0 = fmaxf(acc0[2 * Z], acc0[2 * Z + 1]);
            float v1 = fmaxf(acc1[2 * Z], acc1[2 * Z + 1]);
            v0 = fmaxf(v0, __shfl_xor(v0, 1)); v0 = fmaxf(v0, __shfl_xor(v0, 2));
            v1 = fmaxf(v1, __shfl_xor(v1, 1)); v1 = fmaxf(v1, __shfl_xor(v1, 2));
            pl[0][Z] = v0; pl[1][Z] = v1;
        }
        if ((tid & 3) == 0) {
            #pragma unroll
            for (int hh = 0; hh < 2; ++hh) {
                const int cl = cl0 + hh, c = half * 16 + cl;
                const float bb = bias[c];
                float s0 = 0.0f, q0 = 0.0f;
                #pragma unroll
                for (int Z = 0; Z < 3; ++Z) {
                    const float v = pl[hh][Z] + bb;
                    a2[((size_t)b * 32 + c) * 27 + X * 9 + Y * 3 + Z] = v;
                    s0 += v; q0 += v * v;
                }
                atomicAdd(&s_sum[cl], s0); atomicAdd(&s_ssq[cl], q0);
            }
        }
    }
    __syncthreads();
    if (tid < 16) {
        const int c = half * 16 + tid;
        atomicAdd(&stO[c], s_sum[tid]); atomicAdd(&stO[32 + c], s_ssq[tid]);
    }
}

// ---------- K3: bn2+leaky -> conv3 (32->64, pad1, 3^3) + pool -> [64] + bn3 stats
__global__ __launch_bounds__(256) void k_conv3(const float* __restrict__ a2,
        const float* __restrict__ w, const float* __restrict__ bias,
        const float* __restrict__ bng, const float* __restrict__ bnb,
        const float* __restrict__ stI, float* __restrict__ a3,
        float* __restrict__ stO) {
    __shared__ float x[864];
    __shared__ float pacc[256 * 8];
    __shared__ float sc[32], sh[32];
    const int b = blockIdx.x, tid = threadIdx.x;
    if (tid < 32) {
        const float cnt = 256.0f * 27.0f;
        float m = stI[tid] / cnt;
        float v = stI[32 + tid] / cnt - m * m;
        float s = bng[tid] * rsqrtf(fmaxf(v, 0.0f) + EPS);
        sc[tid] = s; sh[tid] = bnb[tid] - m * s;
    }
    __syncthreads();
    for (int i = tid; i < 864; i += 256) {
        int c = i / 27;
        x[i] = leaky(a2[(size_t)b * 864 + i] * sc[c] + sh[c]);
    }
    __syncthreads();
    const int c = tid & 63, q = tid >> 6;
    float acc[8];
    #pragma unroll
    for (int p = 0; p < 8; ++p) acc[p] = 0.0f;
    for (int ic = q * 8; ic < q * 8 + 8; ++ic) {
        const float* wr = w + ((size_t)c * 32 + ic) * 27;
        #pragma unroll
        for (int d = 0; d < 27; ++d) {
            const int dx = d / 9, dy = (d / 3) % 3, dz = d % 3;
            const float wv = wr[d];
            #pragma unroll
            for (int p = 0; p < 8; ++p) {
                const int px = p >> 2, py = (p >> 1) & 1, pz = p & 1;
                const int ix = px + dx - 1, iy = py + dy - 1, iz = pz + dz - 1;
                if (ix >= 0 && iy >= 0 && iz >= 0)
                    acc[p] += wv * x[ic * 27 + ix * 9 + iy * 3 + iz];
            }
        }
    }
    #pragma unroll
    for (int p = 0; p < 8; ++p) pacc[tid * 8 + p] = acc[p];
    __syncthreads();
    if (q == 0) {
        float m = -1e30f;
        #pragma unroll
        for (int p = 0; p < 8; ++p) {
            float v = pacc[c * 8 + p] + pacc[(64 + c) * 8 + p]
                    + pacc[(128 + c) * 8 + p] + pacc[(192 + c) * 8 + p];
            m = fmaxf(m, v);
        }
        float v = m + bias[c];
        a3[(size_t)b * 64 + c] = v;
        atomicAdd(&stO[c], v); atomicAdd(&stO[64 + c], v * v);
    }
}

// ---------- K4: bn3+leaky -> dense 64->128 (pre-bn4) + bn4 stats
__global__ __launch_bounds__(128) void k_dense1(const float* __restrict__ a3,
        const float* __restrict__ bng, const float* __restrict__ bnb,
        const float* __restrict__ stI,
        const float* __restrict__ w1, const float* __restrict__ b1,
        float* __restrict__ h1, float* __restrict__ stO) {
    __shared__ float x[64];
    const int b = blockIdx.x, tid = threadIdx.x;
    if (tid < 64) {
        float m = stI[tid] / 256.0f;
        float v = stI[64 + tid] / 256.0f - m * m;
        float s = bng[tid] * rsqrtf(fmaxf(v, 0.0f) + EPS);
        x[tid] = leaky(a3[(size_t)b * 64 + tid] * s + (bnb[tid] - m * s));
    }
    __syncthreads();
    const float* wr = w1 + tid * 64;
    float acc = b1[tid];
    #pragma unroll
    for (int i = 0; i < 64; ++i) acc += x[i] * wr[i];
    h1[(size_t)b * 128 + tid] = acc;
    atomicAdd(&stO[tid], acc); atomicAdd(&stO[128 + tid], acc * acc);
}

// ---------- K5: bn4+leaky -> 128->100 (+leaky) -> 100->20 -> out (f32)
__global__ __launch_bounds__(128) void k_dense2(const float* __restrict__ h1,
        const float* __restrict__ bng, const float* __restrict__ bnb,
        const float* __restrict__ stI,
        const float* __restrict__ w2, const float* __restrict__ bias2,
        const float* __restrict__ w3, const float* __restrict__ bias3,
        float* __restrict__ out) {
    __shared__ float x[128];
    __shared__ float y[100];
    const int b = blockIdx.x, tid = threadIdx.x;
    {
        float m = stI[tid] / 256.0f;
        float v = stI[128 + tid] / 256.0f - m * m;
        float s = bng[tid] * rsqrtf(fmaxf(v, 0.0f) + EPS);
        x[tid] = leaky(h1[(size_t)b * 128 + tid] * s + (bnb[tid] - m * s));
    }
    __syncthreads();
    if (tid < 100) {
        const float* wr = w2 + tid * 128;
        float acc = bias2[tid];
        #pragma unroll
        for (int i = 0; i < 128; ++i) acc += x[i] * wr[i];
        y[tid] = leaky(acc);
    }
    __syncthreads();
    if (tid < 20) {
        const float* wr = w3 + tid * 100;
        float acc = bias3[tid];
        #pragma unroll
        for (int i = 0; i < 100; ++i) acc += y[i] * wr[i];
        out[(size_t)b * 20 + tid] = acc;
    }
}

extern "C" void kernel_launch(void* const* d_in, const int* in_sizes, int n_in,
                              void* d_out, int out_size, void* d_ws, size_t ws_size,
                              hipStream_t stream) {
    (void)in_sizes; (void)n_in; (void)out_size; (void)ws_size;
    const float* pos  = (const float*)d_in[0];
    const float* c1w  = (const float*)d_in[1];
    const float* c1b  = (const float*)d_in[2];
    const float* bn1g = (const float*)d_in[3];
    const float* bn1b = (const float*)d_in[4];
    const float* c2w  = (const float*)d_in[5];
    const float* c2b  = (const float*)d_in[6];
    const float* bn2g = (const float*)d_in[7];
    const float* bn2b = (const float*)d_in[8];
    const float* c3w  = (const float*)d_in[9];
    const float* c3b  = (const float*)d_in[10];
    const float* bn3g = (const float*)d_in[11];
    const float* bn3b = (const float*)d_in[12];
    const float* d1w  = (const float*)d_in[13];
    const float* d1b  = (const float*)d_in[14];
    const float* bn4g = (const float*)d_in[15];
    const float* bn4b = (const float*)d_in[16];
    const float* d2w  = (const float*)d_in[17];
    const float* d2b  = (const float*)d_in[18];
    const float* d3w  = (const float*)d_in[19];
    const float* d3b  = (const float*)d_in[20];
    const int* types  = (const int*)d_in[22];   // d_in[21]=batch_ids implied by layout

    float* ws = (float*)d_ws;
    float* st = ws;                         // 480 f bn stats
    float* a1 = ws + 512;                   // 2,985,984 f  [b][729][16]
    u32* fields = (u32*)(a1 + 2985984);     // f16 pairs: 4,478,976 u32 (~30 MB)
    float* a2 = (float*)(fields + 4478976); // 221,184 f
    float* a3 = a2 + 221184;                // 16,384 f
    float* h1 = a3 + 16384;                 // 32,768 f

    k_splat <<<BATCH, 512, 0, stream>>>(pos, types, fields, st);
    k_conv1 <<<9 * BATCH, 256, 0, stream>>>(fields, c1w, c1b, a1, st);
    k_conv2 <<<2 * BATCH, 320, 0, stream>>>(a1, c2w, c2b, bn1g, bn1b, st, a2, st + 32);
    k_conv3 <<<BATCH, 256, 0, stream>>>(a2, c3w, c3b, bn2g, bn2b, st + 32, a3, st + 96);
    k_dense1<<<BATCH, 128, 0, stream>>>(a3, bn3g, bn3b, st + 96, d1w, d1b, h1, st + 224);
    k_dense2<<<BATCH, 128, 0, stream>>>(h1, bn4g, bn4b, st + 224, d2w, d2b, d3w, d3b,
                                        (float*)d_out);
}

// Round 15
// 214.114 us; speedup vs baseline: 1.2591x; 1.0018x over previous
//
#include <hip/hip_runtime.h>

// CavityModel forward: gaussian blur -> 3x(conv3d+maxpool+BN(batch stats)+leaky)
// -> dense 64->128 (+BN+leaky) -> 128->100 (+leaky) -> 100->20.
// R15: R14 + ONE change in conv1's MFMA loop: koff table hoisted to registers
// (48 u16, compile-time indexed) -> halves per-tile LDS ops and breaks the
// koffT->fldP dependency chain. Everything else frozen (R8/R10 lesson).

#define G2 324
#define G3 5832
#define NT 6
#define BATCH 256
#define APE 100
#define EPS 1e-5f

typedef unsigned short u16;
typedef unsigned int u32;
typedef _Float16 f16;
typedef _Float16 h2 __attribute__((ext_vector_type(2)));
typedef _Float16 f16x8 __attribute__((ext_vector_type(8)));
typedef float f32x4 __attribute__((ext_vector_type(4)));

__device__ __forceinline__ float leaky(float x) { return x >= 0.0f ? x : 0.01f * x; }
__device__ __forceinline__ u32 pkh(float a, float b) {
    h2 v; v[0] = (f16)a; v[1] = (f16)b;
    return __builtin_bit_cast(u32, v);
}

// ---------- K1a: gaussian splat, separable outer product, NO atomics.
// block 0 zeroes the bn-stats buffer (runs strictly before all consumers).
__global__ __launch_bounds__(512) void k_splat(const float* __restrict__ pos,
        const int* __restrict__ types, u32* __restrict__ fields,
        float* __restrict__ stO) {
    __shared__ float ew[APE * 54];
    __shared__ float ssum[APE * 3];
    __shared__ int list[APE];
    __shared__ int base[NT + 1];
    __shared__ int cnt[NT], cur[NT];
    const int b = blockIdx.x, tid = threadIdx.x;

    if (b == 0 && tid < 480) stO[tid] = 0.0f;
    if (tid < NT) { cnt[tid] = 0; cur[tid] = 0; }
    __syncthreads();
    if (tid < APE) atomicAdd(&cnt[types[b * APE + tid]], 1);
    if (tid < 300) {
        const int la = tid / 3, ax = tid % 3;
        const float p = pos[(b * APE + la) * 3 + ax];
        float s = 0.0f;
        #pragma unroll
        for (int g = 0; g < 18; ++g) {
            const float d = (float)g - 8.5f - p;
            const float e = __expf(d * d * (-1.0f / 0.72f));
            ew[la * 54 + ax * 18 + g] = e;
            s += e;
        }
        ssum[tid] = s;
    }
    __syncthreads();
    if (tid == 0) {
        int s = 0;
        #pragma unroll
        for (int t = 0; t < NT; ++t) { base[t] = s; s += cnt[t]; }
        base[NT] = s;
    }
    if (tid < APE) {
        const float inv = 1.0f / (ssum[tid * 3] * ssum[tid * 3 + 1] * ssum[tid * 3 + 2]);
        #pragma unroll
        for (int g = 0; g < 18; ++g) ew[tid * 54 + g] *= inv;
    }
    __syncthreads();
    if (tid < APE) {
        const int t = types[b * APE + tid];
        const int j = atomicAdd(&cur[t], 1);
        list[base[t] + j] = tid;
    }
    __syncthreads();

    for (int it = tid; it < NT * 324; it += 512) {
        const int t = it / 324, r = it - t * 324;
        const int i = r / 18, j = r % 18;
        float acc[18];
        #pragma unroll
        for (int k = 0; k < 18; ++k) acc[k] = 0.0f;
        const int e1 = base[t + 1];
        for (int u = base[t]; u < e1; ++u) {
            const int a = list[u];
            const float exy = ew[a * 54 + i] * ew[a * 54 + 18 + j];
            const float* ez = &ew[a * 54 + 36];
            #pragma unroll
            for (int k = 0; k < 18; ++k) acc[k] += exy * ez[k];
        }
        u32* dst = &fields[((size_t)b * NT + t) * 2916 + (size_t)r * 9];
        #pragma unroll
        for (int q = 0; q < 9; ++q) dst[q] = pkh(acc[2 * q], acc[2 * q + 1]);
    }
}

// ---------- K1b: conv1 via MFMA implicit GEMM + 2x2x2 pool + bias + bn1 stats
// block = (env b, x-pair Xg 0..8); grid bx = b*9 + Xg (same-env adjacent).
// input tile fldP[ic 6][plane 4][y 20][z 20] f16, zero-padded halo.
// A = W[16 oc][192 k] (k>=162 zero) in regs; B built per tile via register
// koff (hoisted once from the LDS table; compile-time indexed).
__global__ __launch_bounds__(256, 3) void k_conv1(const u32* __restrict__ fields,
        const float* __restrict__ w, const float* __restrict__ bias,
        float* __restrict__ a1, float* __restrict__ stO) {
    __shared__ f16 fldP[9600];     // 19200 B: [ic][pl][y][z] strides 1600/400/20/1
    __shared__ f16 outB[16 * 648]; // 20736 B: conv out [oc][s], s = oxl*324+oy*18+oz
    __shared__ u16 koffT[192];     // element offsets per k
    __shared__ float bs[16], s_sum[16], s_ssq[16];
    const int bx = blockIdx.x, b = bx / 9, Xg = bx % 9, tid = threadIdx.x;

    for (int i = tid; i < 4800; i += 256) ((u32*)fldP)[i] = 0u;
    if (tid < 192) {
        u16 off = 0;
        if (tid < 162) {
            const int ic = tid / 27, d = tid % 27;
            off = (u16)(ic * 1600 + (d / 9) * 400 + ((d / 3) % 3) * 20 + (d % 3));
        }
        koffT[tid] = off;
    }
    if (tid < 16) { bs[tid] = bias[tid]; s_sum[tid] = 0.0f; s_ssq[tid] = 0.0f; }

    // A fragments: lane m = lane&15 (oc), k = 32c + 8g + j (g = lane>>4)
    const int lane = tid & 63, g = lane >> 4, m = lane & 15, wv = tid >> 6;
    f16x8 af[6];
    #pragma unroll
    for (int c = 0; c < 6; ++c)
        #pragma unroll
        for (int j = 0; j < 8; ++j) {
            const int k = 32 * c + 8 * g + j;
            af[c][j] = (k < 162) ? (f16)w[m * 162 + k] : (f16)0.0f;
        }
    __syncthreads();

    // stage interior: planes ix = 2Xg-1 .. 2Xg+2 (pads stay zero)
    for (int i = tid; i < 3888; i += 256) {
        const int p = i % 9, r2 = i / 9, iy = r2 % 18, r3 = r2 / 18;
        const int pl = r3 & 3, ic = r3 >> 2;
        const int ix = 2 * Xg - 1 + pl;
        if (ix >= 0 && ix < 18) {
            const u32 v = fields[((size_t)(b * 6 + ic) * 324 + ix * 18 + iy) * 9 + p];
            const h2 hv = __builtin_bit_cast(h2, v);
            const int e = ic * 1600 + pl * 400 + (iy + 1) * 20 + (2 * p + 1);
            fldP[e] = hv[0];
            fldP[e + 1] = hv[1];
        }
    }
    __syncthreads();

    // hoist this thread's 48 koff entries into registers (compile-time indexed)
    u16 koffR[48];
    #pragma unroll
    for (int c = 0; c < 6; ++c)
        #pragma unroll
        for (int j = 0; j < 8; ++j)
            koffR[c * 8 + j] = koffT[32 * c + 8 * g + j];

    // MFMA over 41 spatial tiles of 16 (648 positions, last tile ragged)
    for (int t = wv; t < 41; t += 4) {
        const int s = 16 * t + m;
        const int sv = (s < 648) ? s : 647;
        const int oxl = sv / 324, rem = sv % 324, oy = rem / 18, oz = rem % 18;
        // stage writes input (iy,iz) at padded index (iy+1,iz+1); tap needs
        // array index oy+dy (iy=oy+dy-1), koff contributes dy*20+dz -> base oy,oz.
        const int cb = oxl * 400 + oy * 20 + oz;
        f32x4 acc = {0.0f, 0.0f, 0.0f, 0.0f};
        #pragma unroll
        for (int c = 0; c < 6; ++c) {
            f16x8 bf;
            #pragma unroll
            for (int j = 0; j < 8; ++j)
                bf[j] = fldP[cb + (int)koffR[c * 8 + j]];
            acc = __builtin_amdgcn_mfma_f32_16x16x32_f16(af[c], bf, acc, 0, 0, 0);
        }
        if (s < 648) {
            #pragma unroll
            for (int r = 0; r < 4; ++r)
                outB[(4 * g + r) * 648 + s] = (f16)acc[r];
        }
    }
    __syncthreads();

    // 2x2x2 pool + bias -> a1 [b][spatial 729][ch 16] + bn1 stats
    for (int i = tid; i < 1296; i += 256) {
        const int oc = i & 15, sp = i >> 4, Y = sp / 9, Z = sp % 9;
        float mx = -1e30f;
        #pragma unroll
        for (int u = 0; u < 8; ++u) {
            const int ox = u >> 2, dy = (u >> 1) & 1, dz = u & 1;
            mx = fmaxf(mx, (float)outB[oc * 648 + ox * 324
                                       + (2 * Y + dy) * 18 + (2 * Z + dz)]);
        }
        const float v = mx + bs[oc];
        a1[((size_t)b * 729 + Xg * 81 + Y * 9 + Z) * 16 + oc] = v;
        atomicAdd(&s_sum[oc], v);
        atomicAdd(&s_ssq[oc], v * v);
    }
    __syncthreads();
    if (tid < 16) { atomicAdd(&stO[tid], s_sum[tid]); atomicAdd(&stO[16 + tid], s_ssq[tid]); }
}

// ---------- K2: bn1+leaky -> conv2 (16->32, pad0) + pool -> [32,3^3] + bn2 stats
// oc-split: block = (env, half); grid 2*BATCH (same-env adjacent); 320 threads.
__global__ __launch_bounds__(320) void k_conv2(const float* __restrict__ a1,
        const float* __restrict__ w, const float* __restrict__ bias,
        const float* __restrict__ bng, const float* __restrict__ bnb,
        const float* __restrict__ stI, float* __restrict__ a2,
        float* __restrict__ stO) {
    __shared__ float xin[16 * 729];     // 46656 B
    __shared__ float ws2[6912];         // half of weights: 27648 B
    __shared__ float sc[16], sh[16];
    __shared__ float s_sum[16], s_ssq[16];
    const int bx = blockIdx.x, b = bx >> 1, half = bx & 1, tid = threadIdx.x;
    if (tid < 16) {
        const float cnt = 256.0f * 729.0f;
        float m = stI[tid] / cnt;
        float v = stI[16 + tid] / cnt - m * m;
        float s = bng[tid] * rsqrtf(fmaxf(v, 0.0f) + EPS);
        sc[tid] = s; sh[tid] = bnb[tid] - m * s;
        s_sum[tid] = 0.0f; s_ssq[tid] = 0.0f;
    }
    __syncthreads();
    const float* src = a1 + (size_t)b * 729 * 16;
    for (int i = tid; i < 16 * 729; i += 320) {
        const int spb = i >> 4, c = i & 15;
        xin[c * 729 + spb] = leaky(src[i] * sc[c] + sh[c]);
    }
    for (int i = tid; i < 6912; i += 320) ws2[i] = w[half * 6912 + i];
    __syncthreads();
    if (tid < 288) {
        const int oyi = tid & 1, oxi = (tid >> 1) & 1, rest = tid >> 2;
        const int Y = rest % 3, X = (rest / 3) % 3, c2 = rest / 9;   // c2 0..7
        const int ox = 2 * X + oxi, oy = 2 * Y + oyi;   // 0..5
        const int cl0 = 2 * c2, cl1 = cl0 + 1;
        float acc0[6], acc1[6];
        #pragma unroll
        for (int z = 0; z < 6; ++z) { acc0[z] = 0.0f; acc1[z] = 0.0f; }
        for (int ic = 0; ic < 16; ++ic) {
            #pragma unroll
            for (int dx = 0; dx < 3; ++dx) {
                const int ix = ox + dx;
                #pragma unroll
                for (int dy = 0; dy < 3; ++dy) {
                    const int iy = oy + dy;
                    const float* rp = &xin[ic * 729 + ix * 81 + iy * 9];
                    float row[9];
                    #pragma unroll
                    for (int z = 0; z < 9; ++z) row[z] = rp[z];
                    const int wb0 = (cl0 * 16 + ic) * 27 + dx * 9 + dy * 3;
                    const int wb1 = (cl1 * 16 + ic) * 27 + dx * 9 + dy * 3;
                    #pragma unroll
                    for (int dz = 0; dz < 3; ++dz) {
                        const float w0 = ws2[wb0 + dz];
                        const float w1v = ws2[wb1 + dz];
                        #pragma unroll
                        for (int z = 0; z < 6; ++z) {
                            acc0[z] += w0 * row[z + dz];
                            acc1[z] += w1v * row[z + dz];
                        }
                    }
                }
            }
        }
        float pl[2][3];
        #pragma unroll
        for (int Z = 0; Z < 3; ++Z) {
            float v0 = fmaxf(acc0[2 * Z], acc0[2 * Z + 1]);
            float v1 = fmaxf(acc1[2 * Z], acc1[2 * Z + 1]);
            v0 = fmaxf(v0, __shfl_xor(v0, 1)); v0 = fmaxf(v0, __shfl_xor(v0, 2));
            v1 = fmaxf(v1, __shfl_xor(v1, 1)); v1 = fmaxf(v1, __shfl_xor(v1, 2));
            pl[0][Z] = v0; pl[1][Z] = v1;
        }
        if ((tid & 3) == 0) {
            #pragma unroll
            for (int hh = 0; hh < 2; ++hh) {
                const int cl = cl0 + hh, c = half * 16 + cl;
                const float bb = bias[c];
                float s0 = 0.0f, q0 = 0.0f;
                #pragma unroll
                for (int Z = 0; Z < 3; ++Z) {
                    const float v = pl[hh][Z] + bb;
                    a2[((size_t)b * 32 + c) * 27 + X * 9 + Y * 3 + Z] = v;
                    s0 += v; q0 += v * v;
                }
                atomicAdd(&s_sum[cl], s0); atomicAdd(&s_ssq[cl], q0);
            }
        }
    }
    __syncthreads();
    if (tid < 16) {
        const int c = half * 16 + tid;
        atomicAdd(&stO[c], s_sum[tid]); atomicAdd(&stO[32 + c], s_ssq[tid]);
    }
}

// ---------- K3: bn2+leaky -> conv3 (32->64, pad1, 3^3) + pool -> [64] + bn3 stats
__global__ __launch_bounds__(256) void k_conv3(const float* __restrict__ a2,
        const float* __restrict__ w, const float* __restrict__ bias,
        const float* __restrict__ bng, const float* __restrict__ bnb,
        const float* __restrict__ stI, float* __restrict__ a3,
        float* __restrict__ stO) {
    __shared__ float x[864];
    __shared__ float pacc[256 * 8];
    __shared__ float sc[32], sh[32];
    const int b = blockIdx.x, tid = threadIdx.x;
    if (tid < 32) {
        const float cnt = 256.0f * 27.0f;
        float m = stI[tid] / cnt;
        float v = stI[32 + tid] / cnt - m * m;
        float s = bng[tid] * rsqrtf(fmaxf(v, 0.0f) + EPS);
        sc[tid] = s; sh[tid] = bnb[tid] - m * s;
    }
    __syncthreads();
    for (int i = tid; i < 864; i += 256) {
        int c = i / 27;
        x[i] = leaky(a2[(size_t)b * 864 + i] * sc[c] + sh[c]);
    }
    __syncthreads();
    const int c = tid & 63, q = tid >> 6;
    float acc[8];
    #pragma unroll
    for (int p = 0; p < 8; ++p) acc[p] = 0.0f;
    for (int ic = q * 8; ic < q * 8 + 8; ++ic) {
        const float* wr = w + ((size_t)c * 32 + ic) * 27;
        #pragma unroll
        for (int d = 0; d < 27; ++d) {
            const int dx = d / 9, dy = (d / 3) % 3, dz = d % 3;
            const float wv = wr[d];
            #pragma unroll
            for (int p = 0; p < 8; ++p) {
                const int px = p >> 2, py = (p >> 1) & 1, pz = p & 1;
                const int ix = px + dx - 1, iy = py + dy - 1, iz = pz + dz - 1;
                if (ix >= 0 && iy >= 0 && iz >= 0)
                    acc[p] += wv * x[ic * 27 + ix * 9 + iy * 3 + iz];
            }
        }
    }
    #pragma unroll
    for (int p = 0; p < 8; ++p) pacc[tid * 8 + p] = acc[p];
    __syncthreads();
    if (q == 0) {
        float m = -1e30f;
        #pragma unroll
        for (int p = 0; p < 8; ++p) {
            float v = pacc[c * 8 + p] + pacc[(64 + c) * 8 + p]
                    + pacc[(128 + c) * 8 + p] + pacc[(192 + c) * 8 + p];
            m = fmaxf(m, v);
        }
        float v = m + bias[c];
        a3[(size_t)b * 64 + c] = v;
        atomicAdd(&stO[c], v); atomicAdd(&stO[64 + c], v * v);
    }
}

// ---------- K4: bn3+leaky -> dense 64->128 (pre-bn4) + bn4 stats
__global__ __launch_bounds__(128) void k_dense1(const float* __restrict__ a3,
        const float* __restrict__ bng, const float* __restrict__ bnb,
        const float* __restrict__ stI,
        const float* __restrict__ w1, const float* __restrict__ b1,
        float* __restrict__ h1, float* __restrict__ stO) {
    __shared__ float x[64];
    const int b = blockIdx.x, tid = threadIdx.x;
    if (tid < 64) {
        float m = stI[tid] / 256.0f;
        float v = stI[64 + tid] / 256.0f - m * m;
        float s = bng[tid] * rsqrtf(fmaxf(v, 0.0f) + EPS);
        x[tid] = leaky(a3[(size_t)b * 64 + tid] * s + (bnb[tid] - m * s));
    }
    __syncthreads();
    const float* wr = w1 + tid * 64;
    float acc = b1[tid];
    #pragma unroll
    for (int i = 0; i < 64; ++i) acc += x[i] * wr[i];
    h1[(size_t)b * 128 + tid] = acc;
    atomicAdd(&stO[tid], acc); atomicAdd(&stO[128 + tid], acc * acc);
}

// ---------- K5: bn4+leaky -> 128->100 (+leaky) -> 100->20 -> out (f32)
__global__ __launch_bounds__(128) void k_dense2(const float* __restrict__ h1,
        const float* __restrict__ bng, const float* __restrict__ bnb,
        const float* __restrict__ stI,
        const float* __restrict__ w2, const float* __restrict__ bias2,
        const float* __restrict__ w3, const float* __restrict__ bias3,
        float* __restrict__ out) {
    __shared__ float x[128];
    __shared__ float y[100];
    const int b = blockIdx.x, tid = threadIdx.x;
    {
        float m = stI[tid] / 256.0f;
        float v = stI[128 + tid] / 256.0f - m * m;
        float s = bng[tid] * rsqrtf(fmaxf(v, 0.0f) + EPS);
        x[tid] = leaky(h1[(size_t)b * 128 + tid] * s + (bnb[tid] - m * s));
    }
    __syncthreads();
    if (tid < 100) {
        const float* wr = w2 + tid * 128;
        float acc = bias2[tid];
        #pragma unroll
        for (int i = 0; i < 128; ++i) acc += x[i] * wr[i];
        y[tid] = leaky(acc);
    }
    __syncthreads();
    if (tid < 20) {
        const float* wr = w3 + tid * 100;
        float acc = bias3[tid];
        #pragma unroll
        for (int i = 0; i < 100; ++i) acc += y[i] * wr[i];
        out[(size_t)b * 20 + tid] = acc;
    }
}

extern "C" void kernel_launch(void* const* d_in, const int* in_sizes, int n_in,
                              void* d_out, int out_size, void* d_ws, size_t ws_size,
                              hipStream_t stream) {
    (void)in_sizes; (void)n_in; (void)out_size; (void)ws_size;
    const float* pos  = (const float*)d_in[0];
    const float* c1w  = (const float*)d_in[1];
    const float* c1b  = (const float*)d_in[2];
    const float* bn1g = (const float*)d_in[3];
    const float* bn1b = (const float*)d_in[4];
    const float* c2w  = (const float*)d_in[5];
    const float* c2b  = (const float*)d_in[6];
    const float* bn2g = (const float*)d_in[7];
    const float* bn2b = (const float*)d_in[8];
    const float* c3w  = (const float*)d_in[9];
    const float* c3b  = (const float*)d_in[10];
    const float* bn3g = (const float*)d_in[11];
    const float* bn3b = (const float*)d_in[12];
    const float* d1w  = (const float*)d_in[13];
    const float* d1b  = (const float*)d_in[14];
    const float* bn4g = (const float*)d_in[15];
    const float* bn4b = (const float*)d_in[16];
    const float* d2w  = (const float*)d_in[17];
    const float* d2b  = (const float*)d_in[18];
    const float* d3w  = (const float*)d_in[19];
    const float* d3b  = (const float*)d_in[20];
    const int* types  = (const int*)d_in[22];   // d_in[21]=batch_ids implied by layout

    float* ws = (float*)d_ws;
    float* st = ws;                         // 480 f bn stats
    float* a1 = ws + 512;                   // 2,985,984 f  [b][729][16]
    u32* fields = (u32*)(a1 + 2985984);     // f16 pairs: 4,478,976 u32 (~30 MB)
    float* a2 = (float*)(fields + 4478976); // 221,184 f
    float* a3 = a2 + 221184;                // 16,384 f
    float* h1 = a3 + 16384;                 // 32,768 f

    k_splat <<<BATCH, 512, 0, stream>>>(pos, types, fields, st);
    k_conv1 <<<9 * BATCH, 256, 0, stream>>>(fields, c1w, c1b, a1, st);
    k_conv2 <<<2 * BATCH, 320, 0, stream>>>(a1, c2w, c2b, bn1g, bn1b, st, a2, st + 32);
    k_conv3 <<<BATCH, 256, 0, stream>>>(a2, c3w, c3b, bn2g, bn2b, st + 32, a3, st + 96);
    k_dense1<<<BATCH, 128, 0, stream>>>(a3, bn3g, bn3b, st + 96, d1w, d1b, h1, st + 224);
    k_dense2<<<BATCH, 128, 0, stream>>>(h1, bn4g, bn4b, st + 224, d2w, d2b, d3w, d3b,
                                        (float*)d_out);
}